// Round 11
// baseline (36.228 us; speedup 1.0000x reference)
//
#include <hip/hip_runtime.h>

#ifndef __has_builtin
#define __has_builtin(x) 0
#endif

#if __has_builtin(__builtin_amdgcn_sdot4)
#define DOT4(a, b, c) __builtin_amdgcn_sdot4((a), (b), (c), false)
#else
__device__ __forceinline__ int dot4_sw(int a, int b, int c) {
#pragma unroll
    for (int k = 0; k < 4; ++k)
        c += (int)(signed char)((a >> (8 * k)) & 0xff) *
             (int)(signed char)((b >> (8 * k)) & 0xff);
    return c;
}
#define DOT4(a, b, c) dot4_sw((a), (b), (c))
#endif

constexpr int CH   = 256;
constexpr int NPIX = 1024;   // 32*32
constexpr int PR   = 36;     // padded plane rows
constexpr int PC   = 40;     // padded plane cols (16B-aligned stride)
constexpr float BN_EPS = 1e-5f;

// One block per (image-pair, group); 256 threads, 4 px each, 2 images.
//  - weights: SALU-only sign-pack from uniform int loads (no LDS, no barrier)
//  - activations: each thread packs ONLY its own row into zero-padded LDS
//    planes; single barrier; gather is plain aligned reads (no mask VALU)
//  - shortcut loads issued AFTER the barrier (hidden under gather+dot4)
__global__ __launch_bounds__(256, 4)
void bconv(const float* __restrict__ x,
           const float* __restrict__ wgt,
           const float* __restrict__ gamma,
           const float* __restrict__ beta,
           const float* __restrict__ rmean,
           const float* __restrict__ rvar,
           float* __restrict__ out) {
    __shared__ __align__(16) int pk_lds[2][PR][PC];  // zero-padded packed planes

    const int tid  = threadIdx.x;
    const int n0   = (blockIdx.x >> 6) * 2;
    const int g    = blockIdx.x & 63;
    const int pix0 = tid * 4;
    const int row  = pix0 >> 5;
    const int col0 = pix0 & 31;
    const float* xnA = x + n0 * CH * NPIX;
    const float* xnB = xnA + CH * NPIX;
    float* onA = out + n0 * CH * NPIX;
    float* onB = onA + CH * NPIX;

    // ---- issue own-row conv loads for BOTH images (8 float4 in flight) ----
    float4 xvA[4], xvB[4];
#pragma unroll
    for (int ci = 0; ci < 4; ++ci)
        xvA[ci] = *(const float4*)(xnA + (g * 4 + ci) * NPIX + pix0);
#pragma unroll
    for (int ci = 0; ci < 4; ++ci)
        xvB[ci] = *(const float4*)(xnB + (g * 4 + ci) * NPIX + pix0);

    // ---- zero ONLY the plane borders (disjoint from interior writes) ----
    // interior = rows 2..33 x cols 2..33. Borders: rows {0,1} = ints 0..79,
    // rows {34,35} = ints 1360..1439, plus rows 2..33 x cols {0,1,34,35}.
    {
        int* f0 = &pk_lds[0][0][0];
        int* f1 = &pk_lds[1][0][0];
        if (tid < 80) {                // rows 0-1 and 34-35, full width
            f0[tid] = 0; f0[34 * PC + tid] = 0;
            f1[tid] = 0; f1[34 * PC + tid] = 0;
        }
        if (tid < 128) {               // rows 2..33, cols {0,1,34,35}
            const int r = 2 + (tid >> 2);
            const int c = ((tid & 2) ? 34 : 0) + (tid & 1);
            pk_lds[0][r][c] = 0;
            pk_lds[1][r][c] = 0;
        }
    }

    // ---- weights: SALU sign-pack (block-uniform int ops -> s_load/s_cmp) ----
    // sign from float bits: mag==0 -> 0 ; bits<0 -> -1 ; else +1
    const int* wb = (const int*)(wgt + g * 144);  // [c2][ci][tap] ints
    int wq[4][9];
#pragma unroll
    for (int c2 = 0; c2 < 4; ++c2)
#pragma unroll
        for (int t = 0; t < 9; ++t) {
            int pk = 0;
#pragma unroll
            for (int ci = 0; ci < 4; ++ci) {
                const int b = wb[c2 * 36 + ci * 9 + t];
                const int mag = b & 0x7fffffff;
                const int s = (mag == 0) ? 0 : ((b < 0) ? -1 : 1);
                pk |= (s & 0xff) << (8 * ci);
            }
            wq[c2][t] = pk;
        }

    // ---- BN consts (block-uniform; tiny VALU). Exact numpy op order. ----
    float inv[4], bias[4];
#pragma unroll
    for (int ci = 0; ci < 4; ++ci) {
        const int c = g * 4 + ci;
        float r  = __fdiv_rn(1.0f, __fsqrt_rn(__fadd_rn(rvar[c], BN_EPS)));
        inv[ci]  = __fmul_rn(gamma[c], r);
        bias[ci] = __fsub_rn(beta[c], __fmul_rn(rmean[c], inv[ci]));
    }

    // ---- pack own row (once per image) into padded planes ----
    auto pack_to_lds = [&](const float4 xv[4], int img) {
#pragma unroll
        for (int p = 0; p < 4; ++p) {
            int v = 0;
#pragma unroll
            for (int ci = 0; ci < 4; ++ci) {
                float h = __fadd_rn(__fmul_rn(((const float*)&xv[ci])[p], inv[ci]), bias[ci]);
                int s = (h > 0.f) ? 1 : ((h < 0.f) ? -1 : 0);
                v |= (s & 0xff) << (8 * ci);
            }
            pk_lds[img][row + 2][col0 + 2 + p] = v;
        }
    };
    pack_to_lds(xvA, 0);
    pack_to_lds(xvB, 1);

    __syncthreads();   // single barrier: drains only the 8 own-row loads

    // gather: plain aligned LDS reads, zero masking (borders are zero)
    auto gather = [&](int img, int a[3][8]) {
#pragma unroll
        for (int kh = 0; kh < 3; ++kh) {
            const int4 lo = *(const int4*)&pk_lds[img][row + 2 * kh][col0];
            const int4 hi = *(const int4*)&pk_lds[img][row + 2 * kh][col0 + 4];
            a[kh][0] = lo.x; a[kh][1] = lo.y; a[kh][2] = lo.z; a[kh][3] = lo.w;
            a[kh][4] = hi.x; a[kh][5] = hi.y; a[kh][6] = hi.z; a[kh][7] = hi.w;
        }
    };
    auto compute = [&](const int a[3][8], const float4 sc[4], float4 o[4]) {
#pragma unroll
        for (int c2 = 0; c2 < 4; ++c2)
#pragma unroll
            for (int p = 0; p < 4; ++p) {
                int acc = 0;
#pragma unroll
                for (int kh = 0; kh < 3; ++kh)
#pragma unroll
                    for (int kw = 0; kw < 3; ++kw)
                        acc = DOT4(a[kh][p + 2 * kw], wq[c2][kh * 3 + kw], acc);
                ((float*)&o[c2])[p] = __fadd_rn((float)acc, ((const float*)&sc[c2])[p]);
            }
    };

    // ---- image A: sc load issued first, hidden under gather+dot ----
    float4 scA[4];
#pragma unroll
    for (int c2 = 0; c2 < 4; ++c2)
        scA[c2] = *(const float4*)(xnA + (c2 * 64 + g) * NPIX + pix0);
    int aA[3][8];
    gather(0, aA);
    float4 oA[4];
    compute(aA, scA, oA);
#pragma unroll
    for (int c2 = 0; c2 < 4; ++c2)
        *(float4*)(onA + (c2 * 64 + g) * NPIX + pix0) = oA[c2];

    // ---- image B ----
    float4 scB[4];
#pragma unroll
    for (int c2 = 0; c2 < 4; ++c2)
        scB[c2] = *(const float4*)(xnB + (c2 * 64 + g) * NPIX + pix0);
    int aB[3][8];
    gather(1, aB);
    float4 oB[4];
    compute(aB, scB, oB);
#pragma unroll
    for (int c2 = 0; c2 < 4; ++c2)
        *(float4*)(onB + (c2 * 64 + g) * NPIX + pix0) = oB[c2];
}

extern "C" void kernel_launch(void* const* d_in, const int* in_sizes, int n_in,
                              void* d_out, int out_size, void* d_ws, size_t ws_size,
                              hipStream_t stream) {
    const float* x     = (const float*)d_in[0];
    const float* wgt   = (const float*)d_in[1];
    const float* gamma = (const float*)d_in[2];
    const float* beta  = (const float*)d_in[3];
    const float* rmean = (const float*)d_in[4];
    const float* rvar  = (const float*)d_in[5];
    float* out = (float*)d_out;

    const int N = in_sizes[0] / (CH * NPIX);  // 64
    bconv<<<(N / 2) * 64, 256, 0, stream>>>(x, wgt, gamma, beta, rmean, rvar, out);
}